// Round 7
// baseline (146.606 us; speedup 1.0000x reference)
//
#include <hip/hip_runtime.h>
#include <stdint.h>

// Problem constants: B=32, S=10, D=4096, K=8192
#define B_ 32
#define S_ 10
#define D_ 4096
#define K_ 8192
#define RPB 21                 // rows per batch in A: 10 pq + 10 pp + 1 qq
#define M_REAL (B_ * RPB)      // 672

#define BM 128
#define BN 128
#define BK 64
#define M_PAD_MF 768           // 6 tiles of 128
#define KSPLIT 2
#define KHALF (D_ / KSPLIT)    // 2048
#define NSTEP (KHALF / BK)     // 32

typedef _Float16 f16x8 __attribute__((ext_vector_type(8)));
typedef float f32x4 __attribute__((ext_vector_type(4)));
typedef unsigned short us4 __attribute__((ext_vector_type(4)));

__device__ __forceinline__ void async16(const void* g, void* l) {
  __builtin_amdgcn_global_load_lds(
      (const __attribute__((address_space(1))) unsigned int*)g,
      (__attribute__((address_space(3))) unsigned int*)l, 16, 0, 0);
}

__device__ __forceinline__ f16x8 sqcvt(float4 a, float4 b) {
  f16x8 o;
  o[0] = (_Float16)(a.x * a.x); o[1] = (_Float16)(a.y * a.y);
  o[2] = (_Float16)(a.z * a.z); o[3] = (_Float16)(a.w * a.w);
  o[4] = (_Float16)(b.x * b.x); o[5] = (_Float16)(b.y * b.y);
  o[6] = (_Float16)(b.z * b.z); o[7] = (_Float16)(b.w * b.w);
  return o;
}

// ---------------------------------------------------------------------------
// Prepass: build A rows (pq / pp / qq), quantize to a single f16 plane.
// ---------------------------------------------------------------------------
__global__ __launch_bounds__(256)
void build_a_f16(const float* __restrict__ p, const float* __restrict__ q,
                 unsigned short* __restrict__ Af) {
  size_t idx = (size_t)blockIdx.x * 256 + threadIdx.x;  // over M_PAD_MF * 1024 float4s
  int d4 = (int)(idx & 1023);
  int m = (int)(idx >> 10);
  float4 v = make_float4(0.f, 0.f, 0.f, 0.f);
  if (m < M_REAL) {
    int b = m / RPB;
    int r = m - b * RPB;
    const float4* q4 = (const float4*)(q + (size_t)(b * S_ + (S_ - 1)) * D_);
    if (r < S_) {
      const float4* p4 = (const float4*)(p + (size_t)(b * S_ + r) * D_);
      float4 pv = p4[d4]; float4 qv = q4[d4];
      v = make_float4(pv.x * qv.x, pv.y * qv.y, pv.z * qv.z, pv.w * qv.w);
    } else if (r < 2 * S_) {
      const float4* p4 = (const float4*)(p + (size_t)(b * S_ + (r - S_)) * D_);
      float4 pv = p4[d4];
      v = make_float4(pv.x * pv.x, pv.y * pv.y, pv.z * pv.z, pv.w * pv.w);
    } else {
      float4 qv = q4[d4];
      v = make_float4(qv.x * qv.x, qv.y * qv.y, qv.z * qv.z, qv.w * qv.w);
    }
  }
  us4 h;
  ((unsigned short*)&h)[0] = (unsigned short)__builtin_bit_cast(unsigned short, (_Float16)v.x);
  ((unsigned short*)&h)[1] = (unsigned short)__builtin_bit_cast(unsigned short, (_Float16)v.y);
  ((unsigned short*)&h)[2] = (unsigned short)__builtin_bit_cast(unsigned short, (_Float16)v.z);
  ((unsigned short*)&h)[3] = (unsigned short)__builtin_bit_cast(unsigned short, (_Float16)v.w);
  ((us4*)Af)[idx] = h;
}

// ---------------------------------------------------------------------------
// Fused MFMA GEMM: G[ks][m][k] = sum_{d in half ks} Af[m][d] * (W[k][d])^2
// BK=64: 32 MFMA per wave per step, 32 steps.  LDS 48 KB:
//   Abuf0 [0,16K)  Abuf1 [16K,32K)  Wbuf [32K,48K)   -> 3 blocks/CU.
// Step i:
//   1. W fp32 loads (i+1) -> 8 float4 regs         (issued FIRST)
//   2. A-DMA (i+1) x4 -> Abuf[(i+1)&1]             (async, drains at barrier2)
//   3. ds_read frags + 32 MFMA on Abuf[i&1], Wbuf
//   4. barrier1 = lgkmcnt(0) + raw s_barrier       (NO vmcnt drain!)
//   5. sq+cvt W(i+1) (compiler emits counted vmcnt) + ds_write -> Wbuf
//   6. __syncthreads()                             (drains DMA + ds_writes)
// 16B-chunk XOR swizzle, 8 chunks/row:  phys = chunk ^ (row & 7)  (involution,
// applied on DMA source, W ds_write, and all frag ds_reads).
// ---------------------------------------------------------------------------
__global__ __launch_bounds__(256, 3)
void gemm_mfma(const unsigned short* __restrict__ Af, const float* __restrict__ W,
               float* __restrict__ G) {
  __shared__ unsigned short lds[3 * 128 * 64];   // 48 KB
  const int tid = threadIdx.x;
  const int lane = tid & 63;
  const int wid = tid >> 6;
  const int m0 = blockIdx.y * BM;
  const int n0 = blockIdx.x * BN;
  const int ks = blockIdx.z;
  const int d_base = ks * KHALF;

  char* const ldsb = (char*)lds;        // Abuf0 @0, Abuf1 @16384
  char* const ldsWb = ldsb + 32768;     // Wbuf

  // ---- A staging: 4 DMA issues per thread (per wave: 4 KB of the 16 KB tile) ----
  const unsigned short* gpA[4];
  uint32_t ldsoffA[4];
#pragma unroll
  for (int e = 0; e < 4; ++e) {
    int row = wid * 32 + e * 8 + (lane >> 3);
    int pc = lane & 7;                    // physical 16B chunk (linear DMA dest)
    int c = pc ^ (row & 7);               // logical chunk (pre-swizzled source)
    gpA[e] = Af + (size_t)(m0 + row) * D_ + d_base + c * 8;
    ldsoffA[e] = (uint32_t)((wid * 4 + e) * 1024);
  }

  // ---- W staging: thread t -> row r=t>>1, half h=t&1 (32 f16 = 4 chunks) ----
  const int wrow = tid >> 1;
  const int wh = tid & 1;
  const float* gW = W + (size_t)(n0 + wrow) * D_ + d_base + wh * 32;
  uint32_t wbyte[4];
#pragma unroll
  for (int j = 0; j < 4; ++j)
    wbyte[j] = (uint32_t)(wrow * 128 + (((wh * 4 + j) ^ (wrow & 7)) * 16));

  f32x4 acc[4][4];
#pragma unroll
  for (int i = 0; i < 4; ++i)
#pragma unroll
    for (int j = 0; j < 4; ++j) acc[i][j] = (f32x4){0.f, 0.f, 0.f, 0.f};

  const int wm = wid >> 1;        // wave row in 2x2 grid
  const int wn = wid & 1;
  const int frow = lane & 15;
  const int k16 = lane >> 4;
  int aoff[2][4], woff[2][4];     // byte offsets of fragments within a tile
#pragma unroll
  for (int kk = 0; kk < 2; ++kk)
#pragma unroll
    for (int f = 0; f < 4; ++f) {
      int ra = wm * 64 + f * 16 + frow;
      aoff[kk][f] = ra * 128 + (((kk * 4 + k16) ^ (ra & 7)) * 16);
      int rw = wn * 64 + f * 16 + frow;
      woff[kk][f] = rw * 128 + (((kk * 4 + k16) ^ (rw & 7)) * 16);
    }

  const float4* gW4 = (const float4*)gW;

  // ---- prologue: stage step 0 ----
  {
    float4 wv[8];
#pragma unroll
    for (int u = 0; u < 8; ++u) wv[u] = gW4[u];
#pragma unroll
    for (int e = 0; e < 4; ++e) async16(gpA[e], ldsb + ldsoffA[e]);
    *(f16x8*)(ldsWb + wbyte[0]) = sqcvt(wv[0], wv[1]);
    *(f16x8*)(ldsWb + wbyte[1]) = sqcvt(wv[2], wv[3]);
    *(f16x8*)(ldsWb + wbyte[2]) = sqcvt(wv[4], wv[5]);
    *(f16x8*)(ldsWb + wbyte[3]) = sqcvt(wv[6], wv[7]);
  }
  __syncthreads();

  for (int i = 0; i < NSTEP; ++i) {
    const int nstep = (i + 1 < NSTEP) ? (i + 1) : i;   // clamped
    // ---- 1) W fp32 loads for step i+1 (issue first: counted-wait friendly) ----
    float4 wv[8];
#pragma unroll
    for (int u = 0; u < 8; ++u) wv[u] = gW4[nstep * 16 + u];
    // ---- 2) A-DMA for step i+1 into the idle buffer ----
    const uint32_t nb = (uint32_t)(((i + 1) & 1) * 16384);
#pragma unroll
    for (int e = 0; e < 4; ++e)
      async16(gpA[e] + nstep * 64, ldsb + nb + ldsoffA[e]);

    // ---- 3) compute step i from Abuf[i&1], Wbuf ----
    const uint32_t cb = (uint32_t)((i & 1) * 16384);
#pragma unroll
    for (int kk = 0; kk < 2; ++kk) {
      f16x8 aF[4];
#pragma unroll
      for (int f = 0; f < 4; ++f)
        aF[f] = *(const f16x8*)(ldsb + cb + aoff[kk][f]);
#pragma unroll
      for (int nf = 0; nf < 4; ++nf) {
        f16x8 wF = *(const f16x8*)(ldsWb + woff[kk][nf]);
#pragma unroll
        for (int mf = 0; mf < 4; ++mf)
          acc[mf][nf] = __builtin_amdgcn_mfma_f32_16x16x32_f16(aF[mf], wF, acc[mf][nf], 0, 0, 0);
      }
    }

    // ---- 4) barrier1: all W(i)/A(i) LDS reads done; vmcnt NOT drained ----
    asm volatile("s_waitcnt lgkmcnt(0)" ::: "memory");
    __builtin_amdgcn_s_barrier();
    __builtin_amdgcn_sched_barrier(0);

    // ---- 5) sq+cvt W(i+1) and stage into Wbuf ----
    *(f16x8*)(ldsWb + wbyte[0]) = sqcvt(wv[0], wv[1]);
    *(f16x8*)(ldsWb + wbyte[1]) = sqcvt(wv[2], wv[3]);
    *(f16x8*)(ldsWb + wbyte[2]) = sqcvt(wv[4], wv[5]);
    *(f16x8*)(ldsWb + wbyte[3]) = sqcvt(wv[6], wv[7]);

    // ---- 6) barrier2: DMA(i+1) + W writes visible for step i+1 ----
    __syncthreads();
  }

  // ---- C write: row=(lane>>4)*4+r, col=lane&15 (verified gfx950 C/D layout) ----
  float* Gp = G + (size_t)ks * M_PAD_MF * K_;
  const int crow = m0 + wm * 64;
  const int ccol = n0 + wn * 64;
#pragma unroll
  for (int mf = 0; mf < 4; ++mf)
#pragma unroll
    for (int nf = 0; nf < 4; ++nf)
#pragma unroll
      for (int r = 0; r < 4; ++r) {
        int row = crow + mf * 16 + (lane >> 4) * 4 + r;
        int col = ccol + nf * 16 + (lane & 15);
        Gp[(size_t)row * K_ + col] = acc[mf][nf][r];
      }
}

// ---------------------------------------------------------------------------
// Epilogue: sum K-split planes, normalize, transpose-write.
// out[b][k][s] = -dot / (sqrt(pp)*sqrt(qq)*D)
// ---------------------------------------------------------------------------
__global__ __launch_bounds__(256)
void epilogue2(const float* __restrict__ G, float* __restrict__ out) {
  __shared__ float buf[256 * S_];
  const int tid = threadIdx.x;
  const int b = blockIdx.y;
  const int k0 = blockIdx.x * 256;
  const int k = k0 + tid;
  const float* G0 = G + (size_t)b * RPB * K_ + k;
  const float* G1 = G0 + (size_t)M_PAD_MF * K_;
  float nq = sqrtf(G0[20 * K_] + G1[20 * K_]);
#pragma unroll
  for (int s = 0; s < S_; ++s) {
    float dot = G0[s * K_] + G1[s * K_];
    float pp = G0[(S_ + s) * K_] + G1[(S_ + s) * K_];
    buf[tid * S_ + s] = -dot / (sqrtf(pp) * nq * (float)D_);
  }
  __syncthreads();
  float* ob = out + ((size_t)b * K_ + k0) * S_;
  for (int i = tid; i < 256 * S_; i += 256) ob[i] = buf[i];
}

// ===========================================================================
extern "C" void kernel_launch(void* const* d_in, const int* in_sizes, int n_in,
                              void* d_out, int out_size, void* d_ws, size_t ws_size,
                              hipStream_t stream) {
  const float* p = (const float*)d_in[0];
  const float* q = (const float*)d_in[1];
  const float* W = (const float*)d_in[2];
  float* out = (float*)d_out;

  // ws layout: Af [768][4096] f16 (6291456 B) | G [2][768][8192] f32 (50331648 B)
  uint8_t* w = (uint8_t*)d_ws;
  unsigned short* Af = (unsigned short*)w;
  float* G = (float*)(w + 6291456);

  build_a_f16<<<(M_PAD_MF * (D_ / 4)) / 256, 256, 0, stream>>>(p, q, Af);
  dim3 ggrid(K_ / BN, M_PAD_MF / BM, KSPLIT);   // (64, 6, 2) = 768 blocks = 3/CU
  gemm_mfma<<<ggrid, 256, 0, stream>>>(Af, W, G);
  epilogue2<<<dim3(K_ / 256, B_), 256, 0, stream>>>(G, out);
}

// Round 8
// 113.214 us; speedup vs baseline: 1.2950x; 1.2950x over previous
//
#include <hip/hip_runtime.h>
#include <stdint.h>

// Problem constants: B=32, S=10, D=4096, K=8192
#define B_ 32
#define S_ 10
#define D_ 4096
#define K_ 8192
#define RPB 21                 // rows per batch in A: 10 pq + 10 pp + 1 qq
#define M_REAL (B_ * RPB)      // 672

#define BM 128
#define BN 128
#define BK 32
#define M_PAD_MF 768           // 6 tiles of 128
#define KSPLIT 2
#define KHALF (D_ / KSPLIT)    // 2048
#define NSTEP (KHALF / BK)     // 64

typedef _Float16 f16x8 __attribute__((ext_vector_type(8)));
typedef float f32x4 __attribute__((ext_vector_type(4)));
typedef unsigned short us4 __attribute__((ext_vector_type(4)));

__device__ __forceinline__ void async16(const void* g, void* l) {
  __builtin_amdgcn_global_load_lds(
      (const __attribute__((address_space(1))) unsigned int*)g,
      (__attribute__((address_space(3))) unsigned int*)l, 16, 0, 0);
}

// ---------------------------------------------------------------------------
// Prepass: build A rows (pq / pp / qq), quantize to a single f16 plane.
// ---------------------------------------------------------------------------
__global__ __launch_bounds__(256)
void build_a_f16(const float* __restrict__ p, const float* __restrict__ q,
                 unsigned short* __restrict__ Af) {
  size_t idx = (size_t)blockIdx.x * 256 + threadIdx.x;  // over M_PAD_MF * 1024 float4s
  int d4 = (int)(idx & 1023);
  int m = (int)(idx >> 10);
  float4 v = make_float4(0.f, 0.f, 0.f, 0.f);
  if (m < M_REAL) {
    int b = m / RPB;
    int r = m - b * RPB;
    const float4* q4 = (const float4*)(q + (size_t)(b * S_ + (S_ - 1)) * D_);
    if (r < S_) {
      const float4* p4 = (const float4*)(p + (size_t)(b * S_ + r) * D_);
      float4 pv = p4[d4]; float4 qv = q4[d4];
      v = make_float4(pv.x * qv.x, pv.y * qv.y, pv.z * qv.z, pv.w * qv.w);
    } else if (r < 2 * S_) {
      const float4* p4 = (const float4*)(p + (size_t)(b * S_ + (r - S_)) * D_);
      float4 pv = p4[d4];
      v = make_float4(pv.x * pv.x, pv.y * pv.y, pv.z * pv.z, pv.w * pv.w);
    } else {
      float4 qv = q4[d4];
      v = make_float4(qv.x * qv.x, qv.y * qv.y, qv.z * qv.z, qv.w * qv.w);
    }
  }
  us4 h;
  ((unsigned short*)&h)[0] = (unsigned short)__builtin_bit_cast(unsigned short, (_Float16)v.x);
  ((unsigned short*)&h)[1] = (unsigned short)__builtin_bit_cast(unsigned short, (_Float16)v.y);
  ((unsigned short*)&h)[2] = (unsigned short)__builtin_bit_cast(unsigned short, (_Float16)v.z);
  ((unsigned short*)&h)[3] = (unsigned short)__builtin_bit_cast(unsigned short, (_Float16)v.w);
  ((us4*)Af)[idx] = h;
}

// ---------------------------------------------------------------------------
// Fused MFMA GEMM: G[ks][m][k] = sum_{d in half ks} Af[m][d] * (W[k][d])^2
// R6 body (best-so-far) + XCD-locality block remap:
//   flat I -> xcd=I&7, slot=I>>3, n_t = xcd + 8*(slot/12), m_t=(slot%12)>>1,
//   ks=slot&1.  All 12 blocks sharing one n-tile's W panel run on ONE XCD
//   (all 768 blocks co-resident at 3/CU), so W re-reads hit that XCD's L2
//   instead of hammering L3 (was ~768 MB of L3 traffic = the R4-R6 plateau).
// Pipeline: full double-buffer both operands, ONE __syncthreads per step.
// 16B-chunk XOR swizzle  phys_chunk = chunk ^ ((row^(row>>2))&3) on all tiles.
// ---------------------------------------------------------------------------
__global__ __launch_bounds__(256, 3)
void gemm_mfma(const unsigned short* __restrict__ Af, const float* __restrict__ W,
               float* __restrict__ G) {
  __shared__ unsigned short lds[4 * 128 * 32];   // 32 KB
  const int tid = threadIdx.x;
  const int lane = tid & 63;
  const int wid = tid >> 6;

  // ---- XCD-locality remap (bijection on [0,768)) ----
  const int I = blockIdx.x;
  const int xcd = I & 7;
  const int slot = I >> 3;            // 0..95
  const int n_t = xcd + 8 * (slot / 12);
  const int rem = slot % 12;
  const int m_t = rem >> 1;
  const int ks = rem & 1;

  const int m0 = m_t * BM;
  const int n0 = n_t * BN;
  const int d_base = ks * KHALF;

  char* const ldsb = (char*)lds;          // A buffers at 0, 8192
  char* const ldsWb = ldsb + 16384;       // W buffers at 16384, 24576

  // ---- A staging: 2 async DMA issues per k-step, pre-swizzled global src ----
  const unsigned short* gpA[2];
  uint32_t ldsoffA[2];                    // within an A buffer (0..8K)
#pragma unroll
  for (int half = 0; half < 2; ++half) {
    int row = half * 64 + wid * 16 + (lane >> 2);
    int k16l = (lane & 3) ^ ((row ^ (row >> 2)) & 3);
    gpA[half] = Af + (size_t)(m0 + row) * D_ + d_base + k16l * 8;
    ldsoffA[half] = (uint32_t)(half * 4096 + wid * 1024);   // bytes
  }

  // ---- W staging: thread t covers row=t>>1, floats [h*16, h*16+16) ----
  const int wrow = tid >> 1;
  const int wh = tid & 1;
  const float* gW = W + (size_t)(n0 + wrow) * D_ + d_base + wh * 16;
  const int wsz = (wrow ^ (wrow >> 2)) & 3;
  const uint32_t wbyte0 = (uint32_t)(wrow * 64 + ((2 * wh) ^ wsz) * 16);
  const uint32_t wbyte1 = (uint32_t)(wrow * 64 + ((2 * wh + 1) ^ wsz) * 16);

  f32x4 acc[4][4];
#pragma unroll
  for (int i = 0; i < 4; ++i)
#pragma unroll
    for (int j = 0; j < 4; ++j) acc[i][j] = (f32x4){0.f, 0.f, 0.f, 0.f};

  const int wm = wid >> 1;        // wave row in 2x2 grid
  const int wn = wid & 1;
  const int frow = lane & 15;
  const int k16 = lane >> 4;
  int aoff[4], woff[4];           // byte offsets of fragments within a tile
#pragma unroll
  for (int f = 0; f < 4; ++f) {
    int ra = wm * 64 + f * 16 + frow;
    aoff[f] = ra * 64 + ((k16 ^ ((ra ^ (ra >> 2)) & 3)) * 16);
    int rw = wn * 64 + f * 16 + frow;
    woff[f] = rw * 64 + ((k16 ^ ((rw ^ (rw >> 2)) & 3)) * 16);
  }

  // ---- prologue: stage step 0 (A via DMA, W via reg+cvt), exposed once ----
  async16(gpA[0], ldsb + ldsoffA[0]);
  async16(gpA[1], ldsb + ldsoffA[1]);
  {
    float4 w0 = *(const float4*)(gW);
    float4 w1 = *(const float4*)(gW + 4);
    float4 w2 = *(const float4*)(gW + 8);
    float4 w3 = *(const float4*)(gW + 12);
    f16x8 o0, o1;
    o0[0] = (_Float16)(w0.x * w0.x); o0[1] = (_Float16)(w0.y * w0.y);
    o0[2] = (_Float16)(w0.z * w0.z); o0[3] = (_Float16)(w0.w * w0.w);
    o0[4] = (_Float16)(w1.x * w1.x); o0[5] = (_Float16)(w1.y * w1.y);
    o0[6] = (_Float16)(w1.z * w1.z); o0[7] = (_Float16)(w1.w * w1.w);
    o1[0] = (_Float16)(w2.x * w2.x); o1[1] = (_Float16)(w2.y * w2.y);
    o1[2] = (_Float16)(w2.z * w2.z); o1[3] = (_Float16)(w2.w * w2.w);
    o1[4] = (_Float16)(w3.x * w3.x); o1[5] = (_Float16)(w3.y * w3.y);
    o1[6] = (_Float16)(w3.z * w3.z); o1[7] = (_Float16)(w3.w * w3.w);
    *(f16x8*)(ldsWb + wbyte0) = o0;
    *(f16x8*)(ldsWb + wbyte1) = o1;
  }
  __syncthreads();   // step-0 tiles visible

  for (int i = 0; i < NSTEP; ++i) {
    // ---- top: prefetch step i+1 (A-DMA + W fp32 regs) into the idle bufs ----
    const int dn = ((i + 1 < NSTEP) ? (i + 1) : i) * BK;   // clamped (safe reload)
    const uint32_t nb = (uint32_t)(((i + 1) & 1) * 8192);
    async16(gpA[0] + dn, ldsb + nb + ldsoffA[0]);
    async16(gpA[1] + dn, ldsb + nb + ldsoffA[1]);
    float4 w0 = *(const float4*)(gW + dn);
    float4 w1 = *(const float4*)(gW + dn + 4);
    float4 w2 = *(const float4*)(gW + dn + 8);
    float4 w3 = *(const float4*)(gW + dn + 12);

    // ---- compute step i from buf[i&1] ----
    const uint32_t cb = (uint32_t)((i & 1) * 8192);
    f16x8 aF[4];
#pragma unroll
    for (int f = 0; f < 4; ++f)
      aF[f] = *(const f16x8*)(ldsb + cb + aoff[f]);
#pragma unroll
    for (int nf = 0; nf < 4; ++nf) {
      f16x8 wF = *(const f16x8*)(ldsWb + cb + woff[nf]);
#pragma unroll
      for (int mf = 0; mf < 4; ++mf)
        acc[mf][nf] = __builtin_amdgcn_mfma_f32_16x16x32_f16(aF[mf], wF, acc[mf][nf], 0, 0, 0);
    }

    // ---- bottom: cvt + ds_write W(i+1) into Wbuf[!cur] ----
    f16x8 o0, o1;
    o0[0] = (_Float16)(w0.x * w0.x); o0[1] = (_Float16)(w0.y * w0.y);
    o0[2] = (_Float16)(w0.z * w0.z); o0[3] = (_Float16)(w0.w * w0.w);
    o0[4] = (_Float16)(w1.x * w1.x); o0[5] = (_Float16)(w1.y * w1.y);
    o0[6] = (_Float16)(w1.z * w1.z); o0[7] = (_Float16)(w1.w * w1.w);
    o1[0] = (_Float16)(w2.x * w2.x); o1[1] = (_Float16)(w2.y * w2.y);
    o1[2] = (_Float16)(w2.z * w2.z); o1[3] = (_Float16)(w2.w * w2.w);
    o1[4] = (_Float16)(w3.x * w3.x); o1[5] = (_Float16)(w3.y * w3.y);
    o1[6] = (_Float16)(w3.z * w3.z); o1[7] = (_Float16)(w3.w * w3.w);
    *(f16x8*)(ldsWb + nb + wbyte0) = o0;
    *(f16x8*)(ldsWb + nb + wbyte1) = o1;

    __syncthreads();   // single barrier: step i+1 tiles ready, step i reads done
  }

  // ---- C write: row=(lane>>4)*4+r, col=lane&15 (verified gfx950 C/D layout) ----
  float* Gp = G + (size_t)ks * M_PAD_MF * K_;
  const int crow = m0 + wm * 64;
  const int ccol = n0 + wn * 64;
#pragma unroll
  for (int mf = 0; mf < 4; ++mf)
#pragma unroll
    for (int nf = 0; nf < 4; ++nf)
#pragma unroll
      for (int r = 0; r < 4; ++r) {
        int row = crow + mf * 16 + (lane >> 4) * 4 + r;
        int col = ccol + nf * 16 + (lane & 15);
        Gp[(size_t)row * K_ + col] = acc[mf][nf][r];
      }
}

// ---------------------------------------------------------------------------
// Epilogue: sum K-split planes, normalize, transpose-write.
// out[b][k][s] = -dot / (sqrt(pp)*sqrt(qq)*D)
// ---------------------------------------------------------------------------
__global__ __launch_bounds__(256)
void epilogue2(const float* __restrict__ G, float* __restrict__ out) {
  __shared__ float buf[256 * S_];
  const int tid = threadIdx.x;
  const int b = blockIdx.y;
  const int k0 = blockIdx.x * 256;
  const int k = k0 + tid;
  const float* G0 = G + (size_t)b * RPB * K_ + k;
  const float* G1 = G0 + (size_t)M_PAD_MF * K_;
  float nq = sqrtf(G0[20 * K_] + G1[20 * K_]);
#pragma unroll
  for (int s = 0; s < S_; ++s) {
    float dot = G0[s * K_] + G1[s * K_];
    float pp = G0[(S_ + s) * K_] + G1[(S_ + s) * K_];
    buf[tid * S_ + s] = -dot / (sqrtf(pp) * nq * (float)D_);
  }
  __syncthreads();
  float* ob = out + ((size_t)b * K_ + k0) * S_;
  for (int i = tid; i < 256 * S_; i += 256) ob[i] = buf[i];
}

// ===========================================================================
extern "C" void kernel_launch(void* const* d_in, const int* in_sizes, int n_in,
                              void* d_out, int out_size, void* d_ws, size_t ws_size,
                              hipStream_t stream) {
  const float* p = (const float*)d_in[0];
  const float* q = (const float*)d_in[1];
  const float* W = (const float*)d_in[2];
  float* out = (float*)d_out;

  // ws layout: Af [768][4096] f16 (6291456 B) | G [2][768][8192] f32 (50331648 B)
  uint8_t* w = (uint8_t*)d_ws;
  unsigned short* Af = (unsigned short*)w;
  float* G = (float*)(w + 6291456);

  build_a_f16<<<(M_PAD_MF * (D_ / 4)) / 256, 256, 0, stream>>>(p, q, Af);
  gemm_mfma<<<768, 256, 0, stream>>>(Af, W, G);   // 1-D grid, XCD remap inside
  epilogue2<<<dim3(K_ / 256, B_), 256, 0, stream>>>(G, out);
}